// Round 4
// baseline (498.669 us; speedup 1.0000x reference)
//
#include <hip/hip_runtime.h>

#define SEQ   2048
#define EMB   2048
#define NHEAD 16
#define HDIM  128
#define ROWSM 4096  // B*SEQ

typedef float  f32x4  __attribute__((ext_vector_type(4)));
typedef __bf16 bf16x8 __attribute__((ext_vector_type(8)));

__device__ __forceinline__ unsigned short f2bf(float f) {
  union { float f; unsigned int u; } v; v.f = f;
  return (unsigned short)((v.u + 0x7fffu + ((v.u >> 16) & 1u)) >> 16);
}

__device__ __forceinline__ void gload16(const void* g, void* l) {
  __builtin_amdgcn_global_load_lds(
      (__attribute__((address_space(1))) const unsigned int*)g,
      (__attribute__((address_space(3))) unsigned int*)l,
      16, 0, 0);
}

// fp32 -> bf16 bulk convert, 4 elems/thread
__global__ void cvt_bf16(const float* __restrict__ in,
                         unsigned short* __restrict__ out, int n4) {
  int i = blockIdx.x * 256 + threadIdx.x;
  if (i >= n4) return;
  float4 v = ((const float4*)in)[i];
  ushort4 o;
  o.x = f2bf(v.x); o.y = f2bf(v.y); o.z = f2bf(v.z); o.w = f2bf(v.w);
  ((ushort4*)out)[i] = o;
}

// C = A @ B^T. A: MxK bf16 row-major, B: NxK bf16 row-major.
// STORE_F32=0: C bf16; STORE_F32=1: C fp32 + bias.
template <int STORE_F32>
__global__ __launch_bounds__(256, 2) void gemm_nt(
    const unsigned short* __restrict__ A, const unsigned short* __restrict__ B,
    void* __restrict__ Cout, const float* __restrict__ bias,
    int M, int N, int K) {
  __shared__ __align__(16) unsigned short As[128 * 64];
  __shared__ __align__(16) unsigned short Bs[128 * 64];
  const int tid  = threadIdx.x;
  const int lane = tid & 63;
  const int w    = tid >> 6;
  const int m0 = blockIdx.y * 128;
  const int n0 = blockIdx.x * 128;
  const int wm = (w >> 1) * 64;
  const int wn = (w & 1) * 64;
  const int lg = lane >> 4;
  const int lc = lane & 15;

  f32x4 acc[4][4] = {};

  const int srow = lane >> 3;        // 0..7 row within 1KB chunk (8 rows x 128B)
  const int scol = (lane & 7) * 8;   // element col within row

  for (int k0 = 0; k0 < K; k0 += 64) {
    if (k0) __syncthreads();
#pragma unroll
    for (int ii = 0; ii < 4; ++ii) {
      int i = w * 4 + ii;            // 16 chunks of 1KB each per tile
      int r = i * 8 + srow;
      gload16(A + (size_t)(m0 + r) * K + k0 + scol, (char*)As + i * 1024);
      gload16(B + (size_t)(n0 + r) * K + k0 + scol, (char*)Bs + i * 1024);
    }
    __syncthreads();
#pragma unroll
    for (int kk = 0; kk < 2; ++kk) {
      const int co = kk * 32 + lg * 8;
      bf16x8 a[4], b[4];
#pragma unroll
      for (int i = 0; i < 4; ++i)
        a[i] = *(const bf16x8*)(As + (wm + i * 16 + lc) * 64 + co);
#pragma unroll
      for (int j = 0; j < 4; ++j)
        b[j] = *(const bf16x8*)(Bs + (wn + j * 16 + lc) * 64 + co);
#pragma unroll
      for (int i = 0; i < 4; ++i)
#pragma unroll
        for (int j = 0; j < 4; ++j)
          acc[i][j] = __builtin_amdgcn_mfma_f32_16x16x32_bf16(a[i], b[j], acc[i][j], 0, 0, 0);
    }
  }

  const int rb = lg * 4;
#pragma unroll
  for (int i = 0; i < 4; ++i) {
#pragma unroll
    for (int j = 0; j < 4; ++j) {
      int col = n0 + wn + j * 16 + lc;
#pragma unroll
      for (int r = 0; r < 4; ++r) {
        int row = m0 + wm + i * 16 + rb + r;
        if (STORE_F32) {
          ((float*)Cout)[(size_t)row * N + col] = acc[i][j][r] + bias[col];
        } else {
          ((unsigned short*)Cout)[(size_t)row * N + col] = f2bf(acc[i][j][r]);
        }
      }
    }
  }
}

// Causal flash attention. Grid: (SEQ/128, B*H). Block: 256 (4 waves x 32 q-rows).
// Double-buffered K/V LDS, prefetch-ahead (issue loads before compute, V-pack
// after compute), single barrier per tile. All LDS XOR-swizzled; V-write swizzle
// folds dg&7 (STATIC unroll only — runtime-indexed vector extracts go to scratch:
// round-2 lesson, +32MB scratch writes).
// __launch_bounds__(256,2) required: (256,3) caps VGPR at 84 -> accumulator spill.
__global__ __launch_bounds__(256, 2) void attn_causal(
    const unsigned short* __restrict__ Pq, const unsigned short* __restrict__ Pk,
    const unsigned short* __restrict__ Pv, unsigned short* __restrict__ ctx) {
  __shared__ __align__(16) unsigned short Ks[2][64 * 128];   // K tile [kv][d], swizzled
  __shared__ __align__(16) unsigned short Vt[2][128 * 64];   // V^T tile [d][kv], swizzled
  __shared__ __align__(16) unsigned short Ps[4][32 * 64];    // per-wave P [q][kv], swizzled

  const int tid  = threadIdx.x;
  const int lane = tid & 63;
  const int w    = tid >> 6;
  const int lg   = lane >> 4;
  const int lc   = lane & 15;

  const int bh = blockIdx.y;   // b*16 + h
  const int b  = bh >> 4;
  const int h  = bh & 15;
  // complementary pairing: co-scheduled blocks get qt x and 15-x (work balance)
  const int qt = (bh & 16) ? blockIdx.x : (15 - blockIdx.x);
  const int q0 = qt * 128;
  const int qw = q0 + w * 32;

  const size_t hoff = (size_t)bh * SEQ * HDIM;
  const unsigned short* Q  = Pq + hoff;
  const unsigned short* Kh = Pk + hoff;
  const unsigned short* Vh = Pv + hoff;

  // Q fragments: A-layout row=lane&15, k = kk*32 + (lane>>4)*8 + j
  bf16x8 aq[2][4];
#pragma unroll
  for (int mt = 0; mt < 2; ++mt)
#pragma unroll
    for (int kk = 0; kk < 4; ++kk)
      aq[mt][kk] = *(const bf16x8*)(Q + (size_t)(qw + mt * 16 + lc) * HDIM + kk * 32 + lg * 8);

  const float NEG = -3.0e38f;
  float m_r[2][4], l_r[2][4];
  f32x4 o[2][8] = {};
#pragma unroll
  for (int mt = 0; mt < 2; ++mt)
#pragma unroll
    for (int r = 0; r < 4; ++r) { m_r[mt][r] = NEG; l_r[mt][r] = 0.f; }

  const float Cs = 0.12753123161692858f;  // log2(e)/sqrt(128)

  auto stageK = [&](int buf, int kv0) {
#pragma unroll
    for (int ii = 0; ii < 4; ++ii) {
      int i = w * 4 + ii;                 // chunk (1KB = 4 rows)
      int r = i * 4 + lg;                 // row within tile
      int sd = lc ^ (r & 7);              // pre-swizzled global 16B slot
      gload16(Kh + (size_t)(kv0 + r) * HDIM + sd * 8, (char*)&Ks[buf][0] + i * 1024);
    }
  };
  auto loadV = [&](uint4* vr, int kv0) {
#pragma unroll
    for (int uu = 0; uu < 2; ++uu) {
      int u = tid + uu * 256;
      int kp = u >> 4, dg = u & 15;
      int k = kp * 2, d0 = dg * 8;
      vr[uu * 2]     = *(const uint4*)(Vh + (size_t)(kv0 + k) * HDIM + d0);
      vr[uu * 2 + 1] = *(const uint4*)(Vh + (size_t)(kv0 + k + 1) * HDIM + d0);
    }
  };
  auto packV = [&](int buf, const uint4* vr) {
#pragma unroll
    for (int uu = 0; uu < 2; ++uu) {
      int u = tid + uu * 256;
      int kp = u >> 4, dg = u & 15;
      int k = kp * 2, d0 = dg * 8;
      const unsigned short* e0 = (const unsigned short*)&vr[uu * 2];
      const unsigned short* e1 = (const unsigned short*)&vr[uu * 2 + 1];
#pragma unroll
      for (int jj = 0; jj < 8; ++jj) {    // STATIC index only
        int d = d0 + jj;
        int slotswz = (k >> 3) ^ jj ^ (dg & 7);   // (d&7)=jj, (d>>3)&7=dg&7
        int byteoff = d * 128 + (slotswz << 4) + (k & 7) * 2;
        *(unsigned int*)((char*)&Vt[buf][0] + byteoff) =
            (unsigned int)e0[jj] | ((unsigned int)e1[jj] << 16);
      }
    }
  };

  const int ntiles = (q0 >> 6) + 2;
  int cur = 0;
  uint4 vr[4];

  // prologue: stage tile 0
  stageK(0, 0);
  loadV(vr, 0);
  packV(0, vr);
  __syncthreads();

  for (int t = 0; t < ntiles; ++t) {
    const int kv0 = t * 64;
    const bool pf = (t + 1 < ntiles);
    // prefetch next tile: issue loads now, they land during compute
    if (pf) { stageK(cur ^ 1, kv0 + 64); loadV(vr, kv0 + 64); }

    if (kv0 <= qw + 31) {  // wave-uniform: skip fully-masked tiles
      const bool diag = (kv0 + 63 > qw);
      const unsigned short* ks = &Ks[cur][0];
      const unsigned short* vt = &Vt[cur][0];
      // S = Q @ K^T
      f32x4 s[2][4] = {};
#pragma unroll
      for (int kk = 0; kk < 4; ++kk) {
        bf16x8 bk[4];
#pragma unroll
        for (int nt = 0; nt < 4; ++nt) {
          if (!diag || kv0 + nt * 16 <= qw + 31) {
            int row = nt * 16 + lc;
            bk[nt] = *(const bf16x8*)((const char*)ks + row * 256 +
                                      ((((kk << 2) | lg) ^ (row & 7)) << 4));
          }
        }
#pragma unroll
        for (int mt = 0; mt < 2; ++mt)
#pragma unroll
          for (int nt = 0; nt < 4; ++nt)
            if (!diag || kv0 + nt * 16 <= qw + 31)
              s[mt][nt] = __builtin_amdgcn_mfma_f32_16x16x32_bf16(aq[mt][kk], bk[nt], s[mt][nt], 0, 0, 0);
      }
      // causal mask
      if (diag) {
#pragma unroll
        for (int mt = 0; mt < 2; ++mt)
#pragma unroll
          for (int r = 0; r < 4; ++r) {
            int row = qw + mt * 16 + lg * 4 + r;
#pragma unroll
            for (int nt = 0; nt < 4; ++nt) {
              int col = kv0 + nt * 16 + lc;
              if (col > row) s[mt][nt][r] = NEG;
            }
          }
      }
      // online softmax; row spread over 16 lanes (same lane>>4 group)
#pragma unroll
      for (int mt = 0; mt < 2; ++mt) {
#pragma unroll
        for (int r = 0; r < 4; ++r) {
          float rm = fmaxf(fmaxf(s[mt][0][r], s[mt][1][r]),
                           fmaxf(s[mt][2][r], s[mt][3][r]));
          rm = fmaxf(rm, __shfl_xor(rm, 1));
          rm = fmaxf(rm, __shfl_xor(rm, 2));
          rm = fmaxf(rm, __shfl_xor(rm, 4));
          rm = fmaxf(rm, __shfl_xor(rm, 8));
          float mnew = fmaxf(m_r[mt][r], rm);
          float alpha = exp2f((m_r[mt][r] - mnew) * Cs);
          m_r[mt][r] = mnew;
          float ps = 0.f;
#pragma unroll
          for (int nt = 0; nt < 4; ++nt) {
            float p = exp2f((s[mt][nt][r] - mnew) * Cs);
            s[mt][nt][r] = p;
            ps += p;
          }
          ps += __shfl_xor(ps, 1);
          ps += __shfl_xor(ps, 2);
          ps += __shfl_xor(ps, 4);
          ps += __shfl_xor(ps, 8);
          l_r[mt][r] = l_r[mt][r] * alpha + ps;
#pragma unroll
          for (int nt = 0; nt < 8; ++nt) o[mt][nt][r] = o[mt][nt][r] * alpha;
        }
      }
      // P -> per-wave LDS (swizzled write)
      char* pwB = (char*)&Ps[w][0];
#pragma unroll
      for (int mt = 0; mt < 2; ++mt)
#pragma unroll
        for (int r = 0; r < 4; ++r) {
          int row = mt * 16 + lg * 4 + r;
#pragma unroll
          for (int nt = 0; nt < 4; ++nt) {
            int bo = row * 128 + ((((nt << 1) | (lc >> 3)) ^ (row & 7)) << 4) + ((lc * 2) & 15);
            *(unsigned short*)(pwB + bo) = f2bf(s[mt][nt][r]);
          }
        }
      // O += P @ V (swizzled reads; Vt read swizzle has the extra (d>>3)&7 term)
#pragma unroll
      for (int kk = 0; kk < 2; ++kk) {
        if (diag && kv0 + kk * 32 > qw + 31) continue;
        bf16x8 pa[2];
#pragma unroll
        for (int mt = 0; mt < 2; ++mt) {
          int row = mt * 16 + lc;
          pa[mt] = *(const bf16x8*)(pwB + row * 128 + ((((kk << 2) | lg) ^ (row & 7)) << 4));
        }
#pragma unroll
        for (int nt = 0; nt < 8; ++nt) {
          int d = nt * 16 + lc;
          int swz = ((kk << 2) | lg) ^ (d & 7) ^ ((d >> 3) & 7);
          bf16x8 bv = *(const bf16x8*)((const char*)vt + d * 128 + (swz << 4));
#pragma unroll
          for (int mt = 0; mt < 2; ++mt)
            o[mt][nt] = __builtin_amdgcn_mfma_f32_16x16x32_bf16(pa[mt], bv, o[mt][nt], 0, 0, 0);
        }
      }
    }

    // write next tile's V after compute (T14: loads issued early, write late)
    if (pf) packV(cur ^ 1, vr);
    __syncthreads();
    cur ^= 1;
  }

  // epilogue: ctx[b, q, h*128 + d] (the inverse "faithful" reshape)
  unsigned short* outp = ctx + (size_t)b * SEQ * EMB + (size_t)h * HDIM;
#pragma unroll
  for (int mt = 0; mt < 2; ++mt)
#pragma unroll
    for (int r = 0; r < 4; ++r) {
      int row = qw + mt * 16 + lg * 4 + r;
      float inv = 1.0f / l_r[mt][r];
#pragma unroll
      for (int nt = 0; nt < 8; ++nt)
        outp[(size_t)row * EMB + nt * 16 + lc] = f2bf(o[mt][nt][r] * inv);
    }
}

extern "C" void kernel_launch(void* const* d_in, const int* in_sizes, int n_in,
                              void* d_out, int out_size, void* d_ws, size_t ws_size,
                              hipStream_t stream) {
  const float* x  = (const float*)d_in[0];
  const float* Wq = (const float*)d_in[1];
  const float* Wk = (const float*)d_in[2];
  const float* Wv = (const float*)d_in[3];
  const float* Wp = (const float*)d_in[4];
  const float* bp = (const float*)d_in[5];

  char* ws = (char*)d_ws;
  unsigned short* xb = (unsigned short*)ws;                         // 16MB, reused as ctx
  unsigned short* Wb = (unsigned short*)(ws + (size_t)(16u << 20)); // 8MB, recycled
  unsigned short* Pq = (unsigned short*)(ws + (size_t)(24u << 20));
  unsigned short* Pk = (unsigned short*)(ws + (size_t)(40u << 20));
  unsigned short* Pv = (unsigned short*)(ws + (size_t)(56u << 20));

  const int nX4 = ROWSM * EMB / 4;
  const int nW4 = EMB * EMB / 4;

  cvt_bf16<<<nX4 / 256, 256, 0, stream>>>(x, xb, nX4);

  dim3 ggrid(EMB / 128, ROWSM / 128);

  cvt_bf16<<<nW4 / 256, 256, 0, stream>>>(Wq, Wb, nW4);
  gemm_nt<0><<<ggrid, 256, 0, stream>>>(xb, Wb, Pq, nullptr, ROWSM, EMB, EMB);
  cvt_bf16<<<nW4 / 256, 256, 0, stream>>>(Wk, Wb, nW4);
  gemm_nt<0><<<ggrid, 256, 0, stream>>>(xb, Wb, Pk, nullptr, ROWSM, EMB, EMB);
  cvt_bf16<<<nW4 / 256, 256, 0, stream>>>(Wv, Wb, nW4);
  gemm_nt<0><<<ggrid, 256, 0, stream>>>(xb, Wb, Pv, nullptr, ROWSM, EMB, EMB);

  attn_causal<<<dim3(SEQ / 128, 32), 256, 0, stream>>>(Pq, Pk, Pv, xb);

  cvt_bf16<<<nW4 / 256, 256, 0, stream>>>(Wp, Wb, nW4);
  gemm_nt<1><<<ggrid, 256, 0, stream>>>(xb, Wb, d_out, bp, ROWSM, EMB, EMB);
}

// Round 5
// 305.449 us; speedup vs baseline: 1.6326x; 1.6326x over previous
//
#include <hip/hip_runtime.h>

#define SEQ   2048
#define EMB   2048
#define NHEAD 16
#define HDIM  128
#define ROWSM 4096  // B*SEQ

typedef float  f32x4   __attribute__((ext_vector_type(4)));
typedef float  f32x16  __attribute__((ext_vector_type(16)));
typedef __bf16 bf16x8  __attribute__((ext_vector_type(8)));

__device__ __forceinline__ unsigned short f2bf(float f) {
  union { float f; unsigned int u; } v; v.f = f;
  return (unsigned short)((v.u + 0x7fffu + ((v.u >> 16) & 1u)) >> 16);
}
__device__ __forceinline__ unsigned int pk2(float a, float b) {
  return (unsigned int)f2bf(a) | ((unsigned int)f2bf(b) << 16);
}

__device__ __forceinline__ void gload16(const void* g, void* l) {
  __builtin_amdgcn_global_load_lds(
      (__attribute__((address_space(1))) const unsigned int*)g,
      (__attribute__((address_space(3))) unsigned int*)l,
      16, 0, 0);
}

// fp32 -> bf16 bulk convert, 4 elems/thread
__global__ void cvt_bf16(const float* __restrict__ in,
                         unsigned short* __restrict__ out, int n4) {
  int i = blockIdx.x * 256 + threadIdx.x;
  if (i >= n4) return;
  float4 v = ((const float4*)in)[i];
  ushort4 o;
  o.x = f2bf(v.x); o.y = f2bf(v.y); o.z = f2bf(v.z); o.w = f2bf(v.w);
  ((ushort4*)out)[i] = o;
}

// C = A @ B^T. A: MxK bf16 row-major, B: NxK bf16 row-major.
template <int STORE_F32>
__global__ __launch_bounds__(256, 2) void gemm_nt(
    const unsigned short* __restrict__ A, const unsigned short* __restrict__ B,
    void* __restrict__ Cout, const float* __restrict__ bias,
    int M, int N, int K) {
  __shared__ __align__(16) unsigned short As[128 * 64];
  __shared__ __align__(16) unsigned short Bs[128 * 64];
  const int tid  = threadIdx.x;
  const int lane = tid & 63;
  const int w    = tid >> 6;
  const int m0 = blockIdx.y * 128;
  const int n0 = blockIdx.x * 128;
  const int wm = (w >> 1) * 64;
  const int wn = (w & 1) * 64;
  const int lg = lane >> 4;
  const int lc = lane & 15;

  f32x4 acc[4][4] = {};

  const int srow = lane >> 3;
  const int scol = (lane & 7) * 8;

  for (int k0 = 0; k0 < K; k0 += 64) {
    if (k0) __syncthreads();
#pragma unroll
    for (int ii = 0; ii < 4; ++ii) {
      int i = w * 4 + ii;
      int r = i * 8 + srow;
      gload16(A + (size_t)(m0 + r) * K + k0 + scol, (char*)As + i * 1024);
      gload16(B + (size_t)(n0 + r) * K + k0 + scol, (char*)Bs + i * 1024);
    }
    __syncthreads();
#pragma unroll
    for (int kk = 0; kk < 2; ++kk) {
      const int co = kk * 32 + lg * 8;
      bf16x8 a[4], b[4];
#pragma unroll
      for (int i = 0; i < 4; ++i)
        a[i] = *(const bf16x8*)(As + (wm + i * 16 + lc) * 64 + co);
#pragma unroll
      for (int j = 0; j < 4; ++j)
        b[j] = *(const bf16x8*)(Bs + (wn + j * 16 + lc) * 64 + co);
#pragma unroll
      for (int i = 0; i < 4; ++i)
#pragma unroll
        for (int j = 0; j < 4; ++j)
          acc[i][j] = __builtin_amdgcn_mfma_f32_16x16x32_bf16(a[i], b[j], acc[i][j], 0, 0, 0);
    }
  }

  const int rb = lg * 4;
#pragma unroll
  for (int i = 0; i < 4; ++i) {
#pragma unroll
    for (int j = 0; j < 4; ++j) {
      int col = n0 + wn + j * 16 + lc;
#pragma unroll
      for (int r = 0; r < 4; ++r) {
        int row = m0 + wm + i * 16 + rb + r;
        if (STORE_F32) {
          ((float*)Cout)[(size_t)row * N + col] = acc[i][j][r] + bias[col];
        } else {
          ((unsigned short*)Cout)[(size_t)row * N + col] = f2bf(acc[i][j][r]);
        }
      }
    }
  }
}

// Causal flash attention, swapped-QK form (m214 structure).
// Grid: (SEQ/128, B*H). Block: 256 = 4 waves x 32 q-rows.
// S^T = mfma32x32(K,Q): lane&31 = q, regs+hi = kv -> softmax fully in-register
// (31 fmax/add + ONE shfl_xor(32)). P repacked to PV A-frags via pk2 + xor-32
// exchange (STATIC indices only). V^T staged in LDS (round-4 verified swizzle).
// Single-buffered LDS (32KB). T13 defer-max (THR=8) skips O-rescale when
// max-growth is small. __launch_bounds__(256,2): (256,3) spills (round-2).
__global__ __launch_bounds__(256, 2) void attn_causal(
    const unsigned short* __restrict__ Pq, const unsigned short* __restrict__ Pk,
    const unsigned short* __restrict__ Pv, unsigned short* __restrict__ ctx) {
  __shared__ __align__(16) unsigned short Ks[64 * 128];   // K tile [kv][d], swizzled
  __shared__ __align__(16) unsigned short Vt[128 * 64];   // V^T tile [d][kv], swizzled

  const int tid  = threadIdx.x;
  const int lane = tid & 63;
  const int w    = tid >> 6;
  const int ql   = lane & 31;   // q within wave (S-layout) / d within tile (O-layout)
  const int hi   = lane >> 5;
  const int lg   = lane >> 4;   // staging helpers
  const int lc   = lane & 15;

  const int bh = blockIdx.y;
  const int b  = bh >> 4;
  const int h  = bh & 15;
  const int qt = (bh & 16) ? blockIdx.x : (15 - blockIdx.x);  // work pairing
  const int q0 = qt * 128;
  const int qw = q0 + w * 32;
  const int qg = qw + ql;       // this lane's q row (S-layout)

  const size_t hoff = (size_t)bh * SEQ * HDIM;
  const unsigned short* Q  = Pq + hoff;
  const unsigned short* Kh = Pk + hoff;
  const unsigned short* Vh = Pv + hoff;

  // Q as B-fragments: lane holds row q=lane&31, k = d8*16 + hi*8 + j
  bf16x8 bq[8];
#pragma unroll
  for (int d8 = 0; d8 < 8; ++d8)
    bq[d8] = *(const bf16x8*)(Q + (size_t)qg * HDIM + d8 * 16 + hi * 8);

  const float NEG = -3.0e38f;
  f32x16 o[4];
#pragma unroll
  for (int dt = 0; dt < 4; ++dt)
#pragma unroll
    for (int r = 0; r < 16; ++r) o[dt][r] = 0.f;
  float m_r = NEG, l_r = 0.f;

  const float Cs   = 0.12753123161692858f;  // log2(e)/sqrt(128)
  const float TDEF = 62.7f;                 // 8 / Cs (defer-max threshold)

  const int ntiles = (q0 >> 6) + 2;
  for (int t = 0; t < ntiles; ++t) {
    const int kv0 = t * 64;
    if (t) __syncthreads();
    // ---- stage K (global_load_lds, pre-swizzled source; round-1 verified) ----
#pragma unroll
    for (int ii = 0; ii < 4; ++ii) {
      int i = w * 4 + ii;
      int r = i * 4 + lg;
      int sd = lc ^ (r & 7);
      gload16(Kh + (size_t)(kv0 + r) * HDIM + sd * 8, (char*)Ks + i * 1024);
    }
    // ---- stage V transposed (round-4 verified swizzle; STATIC jj only) ----
#pragma unroll
    for (int uu = 0; uu < 2; ++uu) {
      int u = tid + uu * 256;
      int kp = u >> 4, dg = u & 15;
      int k = kp * 2, d0 = dg * 8;
      uint4 r0 = *(const uint4*)(Vh + (size_t)(kv0 + k) * HDIM + d0);
      uint4 r1 = *(const uint4*)(Vh + (size_t)(kv0 + k + 1) * HDIM + d0);
      const unsigned short* e0 = (const unsigned short*)&r0;
      const unsigned short* e1 = (const unsigned short*)&r1;
#pragma unroll
      for (int jj = 0; jj < 8; ++jj) {
        int d = d0 + jj;
        int slotswz = (k >> 3) ^ jj ^ (dg & 7);
        int byteoff = d * 128 + (slotswz << 4) + (k & 7) * 2;
        *(unsigned int*)((char*)Vt + byteoff) =
            (unsigned int)e0[jj] | ((unsigned int)e1[jj] << 16);
      }
    }
    __syncthreads();

    if (kv0 > qw + 31) continue;            // wave-uniform tile skip
    const bool s1on = (kv0 + 32 <= qw + 31);
    const bool diag = (kv0 + 63 > qw);

    // ---- S^T = K @ Q^T : c[s] holds S[kv][q], lane = q, regs = kv ----
    f32x16 c0, c1;
#pragma unroll
    for (int r = 0; r < 16; ++r) { c0[r] = 0.f; c1[r] = s1on ? 0.f : NEG; }
#pragma unroll
    for (int d8 = 0; d8 < 8; ++d8) {
      bf16x8 ak = *(const bf16x8*)((const char*)Ks + ql * 256 +
                                   (((d8 * 2 + hi) ^ (ql & 7)) << 4));
      c0 = __builtin_amdgcn_mfma_f32_32x32x16_bf16(ak, bq[d8], c0, 0, 0, 0);
    }
    if (s1on) {
#pragma unroll
      for (int d8 = 0; d8 < 8; ++d8) {
        bf16x8 ak = *(const bf16x8*)((const char*)Ks + (32 + ql) * 256 +
                                     (((d8 * 2 + hi) ^ (ql & 7)) << 4));
        c1 = __builtin_amdgcn_mfma_f32_32x32x16_bf16(ak, bq[d8], c1, 0, 0, 0);
      }
    }
    // ---- causal mask: per-lane scalar compares (q is lane-resident) ----
    if (diag) {
#pragma unroll
      for (int r = 0; r < 16; ++r) {
        int kvl = (r & 3) + 8 * (r >> 2) + 4 * hi;
        if (kv0 + kvl > qg) c0[r] = NEG;
        if (s1on && kv0 + 32 + kvl > qg) c1[r] = NEG;
      }
    }
    // ---- in-register softmax ----
    float rm = c0[0];
#pragma unroll
    for (int r = 1; r < 16; ++r) rm = fmaxf(rm, c0[r]);
#pragma unroll
    for (int r = 0; r < 16; ++r) rm = fmaxf(rm, c1[r]);
    rm = fmaxf(rm, __shfl_xor(rm, 32));

    if (__any(rm > m_r + TDEF)) {           // T13 defer-max
      float mnew = fmaxf(m_r, rm);
      float alpha = exp2f((m_r - mnew) * Cs);
      m_r = mnew;
      l_r *= alpha;
#pragma unroll
      for (int r = 0; r < 16; ++r) {
        float ar = __shfl(alpha, (r & 3) + 8 * (r >> 2) + 4 * hi);
#pragma unroll
        for (int dt = 0; dt < 4; ++dt) o[dt][r] *= ar;
      }
    }
#pragma unroll
    for (int r = 0; r < 16; ++r) {
      c0[r] = exp2f((c0[r] - m_r) * Cs);
      c1[r] = exp2f((c1[r] - m_r) * Cs);
    }
    float ps = 0.f;
#pragma unroll
    for (int r = 0; r < 16; ++r) ps += c0[r] + c1[r];
    ps += __shfl_xor(ps, 32);
    l_r += ps;

    // ---- repack P -> PV A-fragments (16 kv per step), xor-32 exchange ----
    bf16x8 pa[4];
#pragma unroll
    for (int t4 = 0; t4 < 4; ++t4) {
      const f32x16& cc = (t4 < 2) ? c0 : c1;
      const int rA = (t4 & 1) * 8;
      unsigned int pkL0 = pk2(cc[rA + 0], cc[rA + 1]);
      unsigned int pkL1 = pk2(cc[rA + 2], cc[rA + 3]);
      unsigned int pkH0 = pk2(cc[rA + 4], cc[rA + 5]);
      unsigned int pkH1 = pk2(cc[rA + 6], cc[rA + 7]);
      unsigned int give0 = hi ? pkL0 : pkH0;
      unsigned int give1 = hi ? pkL1 : pkH1;
      unsigned int keep0 = hi ? pkH0 : pkL0;
      unsigned int keep1 = hi ? pkH1 : pkL1;
      unsigned int recv0 = __shfl_xor(give0, 32);
      unsigned int recv1 = __shfl_xor(give1, 32);
      union { unsigned int u[4]; bf16x8 v; } pu;
      pu.u[0] = hi ? recv0 : keep0;
      pu.u[1] = hi ? recv1 : keep1;
      pu.u[2] = hi ? keep0 : recv0;
      pu.u[3] = hi ? keep1 : recv1;
      pa[t4] = pu.v;
    }
    // ---- O += P @ V : lane = d, regs = q ----
#pragma unroll
    for (int t4 = 0; t4 < 4; ++t4) {
      if (diag && kv0 + t4 * 16 > qw + 31) continue;  // wave-uniform
#pragma unroll
      for (int dt = 0; dt < 4; ++dt) {
        int d = dt * 32 + ql;
        bf16x8 bv = *(const bf16x8*)((const char*)Vt + d * 128 +
                                     (((t4 * 2 + hi) ^ (d & 7) ^ ((d >> 3) & 7)) << 4));
        o[dt] = __builtin_amdgcn_mfma_f32_32x32x16_bf16(pa[t4], bv, o[dt], 0, 0, 0);
      }
    }
  }

  // ---- epilogue: normalize rows (broadcast 1/l per q-row) and store ----
  float linv = 1.0f / l_r;
  unsigned short* outp = ctx + (size_t)b * SEQ * EMB + (size_t)h * HDIM;
#pragma unroll
  for (int r = 0; r < 16; ++r) {
    int kvl = (r & 3) + 8 * (r >> 2) + 4 * hi;
    float lr = __shfl(linv, kvl);
    int qrow = qw + kvl;
#pragma unroll
    for (int dt = 0; dt < 4; ++dt)
      outp[(size_t)qrow * EMB + dt * 32 + ql] = f2bf(o[dt][r] * lr);
  }
}

extern "C" void kernel_launch(void* const* d_in, const int* in_sizes, int n_in,
                              void* d_out, int out_size, void* d_ws, size_t ws_size,
                              hipStream_t stream) {
  const float* x  = (const float*)d_in[0];
  const float* Wq = (const float*)d_in[1];
  const float* Wk = (const float*)d_in[2];
  const float* Wv = (const float*)d_in[3];
  const float* Wp = (const float*)d_in[4];
  const float* bp = (const float*)d_in[5];

  char* ws = (char*)d_ws;
  unsigned short* xb = (unsigned short*)ws;                         // 16MB, reused as ctx
  unsigned short* Wb = (unsigned short*)(ws + (size_t)(16u << 20)); // 8MB, recycled
  unsigned short* Pq = (unsigned short*)(ws + (size_t)(24u << 20));
  unsigned short* Pk = (unsigned short*)(ws + (size_t)(40u << 20));
  unsigned short* Pv = (unsigned short*)(ws + (size_t)(56u << 20));

  const int nX4 = ROWSM * EMB / 4;
  const int nW4 = EMB * EMB / 4;

  cvt_bf16<<<nX4 / 256, 256, 0, stream>>>(x, xb, nX4);

  dim3 ggrid(EMB / 128, ROWSM / 128);

  cvt_bf16<<<nW4 / 256, 256, 0, stream>>>(Wq, Wb, nW4);
  gemm_nt<0><<<ggrid, 256, 0, stream>>>(xb, Wb, Pq, nullptr, ROWSM, EMB, EMB);
  cvt_bf16<<<nW4 / 256, 256, 0, stream>>>(Wk, Wb, nW4);
  gemm_nt<0><<<ggrid, 256, 0, stream>>>(xb, Wb, Pk, nullptr, ROWSM, EMB, EMB);
  cvt_bf16<<<nW4 / 256, 256, 0, stream>>>(Wv, Wb, nW4);
  gemm_nt<0><<<ggrid, 256, 0, stream>>>(xb, Wb, Pv, nullptr, ROWSM, EMB, EMB);

  attn_causal<<<dim3(SEQ / 128, 32), 256, 0, stream>>>(Pq, Pk, Pv, xb);

  cvt_bf16<<<nW4 / 256, 256, 0, stream>>>(Wp, Wb, nW4);
  gemm_nt<1><<<ggrid, 256, 0, stream>>>(xb, Wb, d_out, bp, ROWSM, EMB, EMB);
}